// Round 2
// baseline (447.970 us; speedup 1.0000x reference)
//
#include <hip/hip_runtime.h>
#include <hip/hip_cooperative_groups.h>

// DeterministicEncoder: MLP encoder [M,2]->[M,64] + Laplace-kernel attention.
// exp(-|k-q|) factorizes: sort context by k, build exclusive-prefix Lo and
// suffix Hi sums of exp(+/-k)*v; out[n] = e^{-q}Lo[j] + e^{q}Hi[j], j = rank
// of q among keys. O(N*M*OUT) -> O(M^2/P rank + (M+N)*OUT).
//
// Round 2: fuse all 5 phases + memset into ONE cooperative kernel (round-1
// profile showed dispatch overhead dominating: ~15us of compute inside 148us).
// Atomic-free rank (partials array) removes the memset; vT stored transposed
// so the per-channel scan gathers stay in a 32KB L1-resident window.

#define H    16
#define OUTD 64

namespace cg = cooperative_groups;

__global__ __launch_bounds__(256, 4) void fused_kernel(
    const float* __restrict__ xc, const float* __restrict__ yc,
    const float* __restrict__ xt,
    const float* __restrict__ W1, const float* __restrict__ b1,
    const float* __restrict__ W2, const float* __restrict__ b2,
    const float* __restrict__ W3, const float* __restrict__ b3,
    float* __restrict__ out,
    float* __restrict__ vT, float* __restrict__ skey, int* __restrict__ perm,
    int* __restrict__ rank_part, float* __restrict__ Lo, float* __restrict__ Hi,
    int M, int N)
{
    cg::grid_group grid = cg::this_grid();
    __shared__ float sh[256];          // union: key tile (phase 1) / scan sums (phase 3)
    const int t = threadIdx.x;
    const int gstride = gridDim.x * 256;

    // ---- Phase 1a: rank partials. 1024 units = 32 m-blocks x 32 key-segs.
    // rank_part[seg][m] = #{keys in seg strictly before key[m] in (key,idx) order}
    for (int u = blockIdx.x; u < 1024; u += gridDim.x) {
        const int mblk = u >> 5, seg = u & 31;
        __syncthreads();                       // protect sh from previous unit
        sh[t] = xc[seg * 256 + t];
        __syncthreads();
        const int m = mblk * 256 + t;
        const float mk = xc[m];
        int cnt = 0;
#pragma unroll 4
        for (int j = 0; j < 256; j += 4) {
            float4 k4 = *(const float4*)(sh + j);   // uniform addr -> LDS broadcast
            int g = seg * 256 + j;
            cnt += (k4.x < mk || (k4.x == mk && (g + 0) < m)) ? 1 : 0;
            cnt += (k4.y < mk || (k4.y == mk && (g + 1) < m)) ? 1 : 0;
            cnt += (k4.z < mk || (k4.z == mk && (g + 2) < m)) ? 1 : 0;
            cnt += (k4.w < mk || (k4.w == mk && (g + 3) < m)) ? 1 : 0;
        }
        rank_part[seg * M + m] = cnt;
    }

    // ---- Phase 1b: MLP, one thread per row, 32 units of 256 rows.
    // Weights indexed uniformly -> scalar (s_load) reads. Stores vT[c][m].
    for (int u = blockIdx.x; u < 32; u += gridDim.x) {
        const int m = u * 256 + t;
        const float x = xc[m], y = yc[m];
        float h1[H], h2[H];
#pragma unroll
        for (int j = 0; j < H; j++) {
            float a = x * W1[j] + y * W1[H + j] + b1[j];
            h1[j] = a > 0.f ? a : 0.f;
        }
#pragma unroll
        for (int j = 0; j < H; j++) {
            float a = b2[j];
#pragma unroll
            for (int i = 0; i < H; i++) a += h1[i] * W2[i * H + j];
            h2[j] = a > 0.f ? a : 0.f;
        }
#pragma unroll
        for (int cb = 0; cb < OUTD; cb += 16) {   // 16-ch chunks keep VGPR < 128
            float acc[16];
#pragma unroll
            for (int c = 0; c < 16; c++) acc[c] = b3[cb + c];
#pragma unroll
            for (int i = 0; i < H; i++) {
                float h = h2[i];
#pragma unroll
                for (int c = 0; c < 16; c++) acc[c] += h * W3[i * OUTD + cb + c];
            }
#pragma unroll
            for (int c = 0; c < 16; c++) vT[(size_t)(cb + c) * M + m] = acc[c];
        }
    }

    __threadfence();
    grid.sync();

    // ---- Phase 2: total rank -> scatter into sorted order.
    for (int m = blockIdx.x * 256 + t; m < M; m += gstride) {
        int r = 0;
#pragma unroll 8
        for (int s = 0; s < 32; s++) r += rank_part[s * M + m];   // coalesced
        skey[r] = xc[m];
        perm[r] = m;
    }

    __threadfence();
    grid.sync();

    // ---- Phase 3: per-channel scans. Unit u<64: Lo channel u; u>=64: Hi.
    // Lo[j] = sum_{i<j} exp(s_i) v[perm(i)][c]   (exclusive; Lo[M] = total)
    // Hi[j] = sum_{i>=j} exp(-s_i) v[perm(i)][c] (Hi[M] = 0)
    for (int u = blockIdx.x; u < 128; u += gridDim.x) {
        const int c = u & 63;
        const bool isHi = u >= 64;
        const int base = t * 32;
        float w[32];
        float S = 0.f;
#pragma unroll 4
        for (int r = 0; r < 32; r++) {
            int i = base + r;
            int pos = isHi ? (M - 1 - i) : i;
            float s = skey[pos];
            float e = __expf(isHi ? -s : s);
            float wv = e * vT[(size_t)c * M + perm[pos]];  // gather in 32KB window
            w[r] = wv;
            S += wv;
        }
        __syncthreads();                 // protect sh from previous unit/phase
        sh[t] = S;
        __syncthreads();
        for (int off = 1; off < 256; off <<= 1) {   // Hillis-Steele block scan
            float a = (t >= off) ? sh[t - off] : 0.f;
            __syncthreads();
            sh[t] += a;
            __syncthreads();
        }
        float run = sh[t] - S;           // exclusive offset of this chunk
        if (!isHi) {
#pragma unroll 4
            for (int r = 0; r < 32; r++) {
                Lo[(size_t)(base + r) * OUTD + c] = run;
                run += w[r];
            }
            if (t == 255) Lo[(size_t)M * OUTD + c] = run;
        } else {
#pragma unroll 4
            for (int r = 0; r < 32; r++) {
                run += w[r];
                Hi[(size_t)(M - 1 - (base + r)) * OUTD + c] = run;
            }
            if (t == 0) Hi[(size_t)M * OUTD + c] = 0.f;
        }
    }

    __threadfence();
    grid.sync();

    // ---- Phase 4: query. Wave-uniform binary search (64 lanes share n),
    // then coalesced 256B Lo/Hi row reads + 256B out write.
    const int total = N * OUTD;
    for (int tid = blockIdx.x * 256 + t; tid < total; tid += gstride) {
        int n = tid >> 6, c = tid & 63;
        float q = xt[n];
        int lo = 0, hi = M;               // lower_bound: ties -> Hi side (e^0=1)
        while (lo < hi) {
            int mid = (lo + hi) >> 1;
            if (skey[mid] < q) lo = mid + 1; else hi = mid;
        }
        out[tid] = __expf(-q) * Lo[(size_t)lo * OUTD + c]
                 + __expf(q)  * Hi[(size_t)lo * OUTD + c];
    }
}

extern "C" void kernel_launch(void* const* d_in, const int* in_sizes, int n_in,
                              void* d_out, int out_size, void* d_ws, size_t ws_size,
                              hipStream_t stream)
{
    const float* xc = (const float*)d_in[0];
    const float* yc = (const float*)d_in[1];
    const float* xt = (const float*)d_in[2];
    const float* W1 = (const float*)d_in[3];
    const float* b1 = (const float*)d_in[4];
    const float* W2 = (const float*)d_in[5];
    const float* b2 = (const float*)d_in[6];
    const float* W3 = (const float*)d_in[7];
    const float* b3 = (const float*)d_in[8];
    float* out = (float*)d_out;

    int M = in_sizes[0];
    int N = in_sizes[2];

    // workspace carve-up: vT (2MB) | skey (32KB) | perm (32KB) |
    // rank_part (1MB) | Lo (2.1MB) | Hi (2.1MB)  -> ~7.3MB
    char* ws = (char*)d_ws;
    float* vT        = (float*)ws;
    float* skey      = (float*)(ws + (size_t)M * OUTD * 4);
    int*   perm      = (int*)  ((char*)skey + (size_t)M * 4);
    int*   rank_part = (int*)  ((char*)perm + (size_t)M * 4);
    float* Lo        = (float*)((char*)rank_part + (size_t)32 * M * 4);
    float* Hi        = Lo + (size_t)(M + 1) * OUTD;

    // grid = exactly the co-resident capacity (coop launch can't be rejected;
    // all phases are grid-stride so any grid size is correct). Host-query cost
    // is irrelevant: this code runs once at graph capture.
    int dev = 0;
    hipGetDevice(&dev);
    int numCU = 0;
    hipDeviceGetAttribute(&numCU, hipDeviceAttributeMultiprocessorCount, dev);
    int occ = 0;
    hipOccupancyMaxActiveBlocksPerMultiprocessor(&occ, (const void*)fused_kernel, 256, 0);
    if (occ < 1) occ = 1;
    int NB = occ * (numCU > 0 ? numCU : 256);
    if (NB > 1024) NB = 1024;

    void* args[] = {
        (void*)&xc, (void*)&yc, (void*)&xt,
        (void*)&W1, (void*)&b1, (void*)&W2, (void*)&b2, (void*)&W3, (void*)&b3,
        (void*)&out, (void*)&vT, (void*)&skey, (void*)&perm,
        (void*)&rank_part, (void*)&Lo, (void*)&Hi, (void*)&M, (void*)&N
    };
    hipLaunchCooperativeKernel((void*)fused_kernel, dim3(NB), dim3(256),
                               args, 0, stream);
}

// Round 3
// 126.860 us; speedup vs baseline: 3.5312x; 3.5312x over previous
//
#include <hip/hip_runtime.h>

// DeterministicEncoder: MLP encoder [M,2]->[M,64] + Laplace-kernel attention.
// exp(-|k-q|) factorizes: with context sorted by key, exclusive-prefix
// Lo[j] = sum_{i<j} e^{s_i} v_i and suffix Hi[j] = sum_{i>=j} e^{-s_i} v_i give
// out[n] = e^{-q} Lo[j_n] + e^{q} Hi[j_n], j_n = lower_bound(skey, q).
//
// Round 3: round 2 showed cg::grid.sync() costs ~200us each on gfx950
// (per-workgroup L2 writeback/invalidate storms; VALUBusy was 2% of 610us).
// => back to plain dispatches, but only TWO, with no memset and no atomics:
//   K1: per-block full rank (LDS key broadcast) + direct scatter + MLP.
//   K2: per-channel Lo/Hi scan entirely in LDS + query answered from LDS.

#define H    16
#define OUTD 64
#define MM   8192                 // context/target count, fixed by harness
#define PAD(i) ((i) + ((i) >> 5)) // LDS bank-conflict padding for stride-32 use

// ---------------------------------------------------------------- K1
// 256 blocks. Block b: ranks+scatter for m in [32b, 32b+32), MLP for same rows.
__global__ __launch_bounds__(256) void rank_mlp_kernel(
    const float* __restrict__ xc, const float* __restrict__ yc,
    const float* __restrict__ W1, const float* __restrict__ b1,
    const float* __restrict__ W2, const float* __restrict__ b2,
    const float* __restrict__ W3, const float* __restrict__ b3,
    float* __restrict__ vT, float* __restrict__ skey, int* __restrict__ perm)
{
    __shared__ float sk[MM];      // all keys, 32 KB
    __shared__ int   red[256];
    const int t = threadIdx.x;
    const int b = blockIdx.x;

    for (int i = t; i < MM; i += 256) sk[i] = xc[i];
    __syncthreads();

    // rank: part = t>>5 scans keys [1024*part, +1024); ml = t&31 picks the row.
    // Adjacent lanes share `part` -> identical LDS addresses -> broadcast, free.
    {
        const int part = t >> 5, ml = t & 31;
        const int m = b * 32 + ml;
        const float mk = sk[m];
        const int base = part * 1024;
        int cnt = 0;
#pragma unroll 4
        for (int j = 0; j < 1024; j += 4) {
            float4 k4 = *(const float4*)(sk + base + j);
            const int g = base + j;
            // strict total order on (key, index) -> rank is a permutation
            cnt += (k4.x < mk || (k4.x == mk && (g + 0) < m)) ? 1 : 0;
            cnt += (k4.y < mk || (k4.y == mk && (g + 1) < m)) ? 1 : 0;
            cnt += (k4.z < mk || (k4.z == mk && (g + 2) < m)) ? 1 : 0;
            cnt += (k4.w < mk || (k4.w == mk && (g + 3) < m)) ? 1 : 0;
        }
        red[t] = cnt;
    }
    __syncthreads();
    if (t < 32) {
        const int m = b * 32 + t;
        int r = 0;
#pragma unroll
        for (int p = 0; p < 8; p++) r += red[p * 32 + t];
        skey[r] = sk[m];
        perm[r] = m;
    }

    // MLP: 8 threads per row; each computes h1,h2 (redundant) + 8 channels.
    {
        const int ml = t >> 3, part = t & 7;
        const int m = b * 32 + ml;
        const float x = sk[m], y = yc[m];
        float h1[H], h2[H];
#pragma unroll
        for (int j = 0; j < H; j++) {
            float a = x * W1[j] + y * W1[H + j] + b1[j];
            h1[j] = a > 0.f ? a : 0.f;
        }
#pragma unroll
        for (int j = 0; j < H; j++) {
            float a = b2[j];
#pragma unroll
            for (int i = 0; i < H; i++) a += h1[i] * W2[i * H + j];
            h2[j] = a > 0.f ? a : 0.f;
        }
        const int cb = part * 8;
        float acc[8];
#pragma unroll
        for (int c = 0; c < 8; c++) acc[c] = b3[cb + c];
#pragma unroll
        for (int i = 0; i < H; i++) {
            const float h = h2[i];
#pragma unroll
            for (int c = 0; c < 8; c++) acc[c] += h * W3[i * OUTD + cb + c];
        }
#pragma unroll
        for (int c = 0; c < 8; c++) vT[(size_t)(cb + c) * MM + m] = acc[c];
    }
}

// ---------------------------------------------------------------- K2
// 256 blocks = 64 channels x 4 target-quarters. Scan Lo/Hi for channel c in
// LDS (redundant per quarter, ~free), then answer 2048 targets from LDS.
__global__ __launch_bounds__(256) void scan_query_kernel(
    const float* __restrict__ xt, const float* __restrict__ skey,
    const int* __restrict__ perm, const float* __restrict__ vT,
    float* __restrict__ out, int N)
{
    __shared__ float sk [PAD(MM) + 1];
    __shared__ float sLo[PAD(MM) + 1];
    __shared__ float sHi[PAD(MM) + 1];
    __shared__ float red[256];
    const int t = threadIdx.x;
    const int c = blockIdx.x & 63;
    const int quarter = blockIdx.x >> 6;
    const float* __restrict__ vrow = vT + (size_t)c * MM;

    for (int i = t; i < MM; i += 256) sk[PAD(i)] = skey[i];
    __syncthreads();

    const int base = t * 32;
    int pm[32];
    {
        const int4* pp = (const int4*)(perm + base);
#pragma unroll
        for (int r4 = 0; r4 < 8; r4++) {
            int4 p4 = pp[r4];
            pm[r4 * 4 + 0] = p4.x; pm[r4 * 4 + 1] = p4.y;
            pm[r4 * 4 + 2] = p4.z; pm[r4 * 4 + 3] = p4.w;
        }
    }

    // ---- Lo: exclusive prefix of e^{s} v
    float w[32];
    float S = 0.f;
#pragma unroll 4
    for (int r = 0; r < 32; r++) {
        float wv = __expf(sk[PAD(base + r)]) * vrow[pm[r]];
        w[r] = wv; S += wv;
    }
    red[t] = S;
    __syncthreads();
    for (int off = 1; off < 256; off <<= 1) {      // inclusive prefix scan
        float a = (t >= off) ? red[t - off] : 0.f;
        __syncthreads();
        red[t] += a;
        __syncthreads();
    }
    float run = red[t] - S;                         // exclusive chunk offset
#pragma unroll 4
    for (int r = 0; r < 32; r++) { sLo[PAD(base + r)] = run; run += w[r]; }
    if (t == 255) sLo[PAD(MM)] = run;
    __syncthreads();                                // red reuse barrier

    // ---- Hi: suffix of e^{-s} v
    float S2 = 0.f;
#pragma unroll 4
    for (int r = 0; r < 32; r++) {
        float wv = __expf(-sk[PAD(base + r)]) * vrow[pm[r]];  // L1-hot regather
        w[r] = wv; S2 += wv;
    }
    red[t] = S2;
    __syncthreads();
    for (int off = 1; off < 256; off <<= 1) {      // inclusive suffix scan
        float a = (t + off < 256) ? red[t + off] : 0.f;
        __syncthreads();
        red[t] += a;
        __syncthreads();
    }
    run = red[t] - S2;                              // chunks strictly after t
#pragma unroll 4
    for (int r = 31; r >= 0; r--) { run += w[r]; sHi[PAD(base + r)] = run; }
    if (t == 0) sHi[PAD(MM)] = 0.f;
    __syncthreads();

    // ---- query: uniform-depth (13-step) lower_bound in LDS, out from LDS.
    const int n0 = quarter * (MM / 4);
#pragma unroll
    for (int k = 0; k < MM / 4 / 256; k++) {
        const int n = n0 + k * 256 + t;
        const float q = xt[n];
        int lo = 0, hi = MM;
        while (lo < hi) {
            const int mid = (lo + hi) >> 1;
            if (sk[PAD(mid)] < q) lo = mid + 1; else hi = mid;
        }
        out[(size_t)n * OUTD + c] = __expf(-q) * sLo[PAD(lo)]
                                  + __expf(q)  * sHi[PAD(lo)];
    }
}

extern "C" void kernel_launch(void* const* d_in, const int* in_sizes, int n_in,
                              void* d_out, int out_size, void* d_ws, size_t ws_size,
                              hipStream_t stream)
{
    const float* xc = (const float*)d_in[0];
    const float* yc = (const float*)d_in[1];
    const float* xt = (const float*)d_in[2];
    const float* W1 = (const float*)d_in[3];
    const float* b1 = (const float*)d_in[4];
    const float* W2 = (const float*)d_in[5];
    const float* b2 = (const float*)d_in[6];
    const float* W3 = (const float*)d_in[7];
    const float* b3 = (const float*)d_in[8];
    float* out = (float*)d_out;
    const int N = in_sizes[2];   // 8192

    // workspace: vT [64][MM] (2MB) | skey [MM] | perm [MM]
    char* ws = (char*)d_ws;
    float* vT   = (float*)ws;
    float* skey = (float*)(ws + (size_t)OUTD * MM * 4);
    int*   perm = (int*)  (ws + (size_t)OUTD * MM * 4 + (size_t)MM * 4);

    rank_mlp_kernel<<<256, 256, 0, stream>>>(xc, yc, W1, b1, W2, b2, W3, b3,
                                             vT, skey, perm);
    scan_query_kernel<<<256, 256, 0, stream>>>(xt, skey, perm, vT, out, N);
}

// Round 4
// 123.829 us; speedup vs baseline: 3.6176x; 1.0245x over previous
//
#include <hip/hip_runtime.h>

// DeterministicEncoder: MLP encoder [M,2]->[M,64] + Laplace-kernel attention.
// exp(-|k-q|) factorizes: with context sorted by key, exclusive-prefix
// Lo[j] = sum_{i<j} e^{s_i} v_i and suffix Hi[j] = sum_{i>=j} e^{-s_i} v_i give
// out[n] = e^{-q} Lo[j_n] + e^{q} Hi[j_n], j_n = lower_bound(skey, q).
//
// Round 4: keep the 2-dispatch structure (round 2 proved cg::grid.sync() is
// ~100us+ on gfx950; round1->3 delta proved ~5us/dispatch). K2 changes:
//   - value row staged to LDS via one coalesced 32KB copy; the perm-gather
//     becomes an LDS gather (random banks ~2-way = free) instead of a
//     64-lane-divergent global load,
//   - gather ONCE into vv[32] registers, reused by both Lo and Hi passes
//     (round 3 re-gathered for the Hi pass).

#define H    16
#define OUTD 64
#define MM   8192                 // context/target count, fixed by harness
#define PAD(i) ((i) + ((i) >> 5)) // LDS bank padding for stride-32 access

// ---------------------------------------------------------------- K1
// 256 blocks. Block b: ranks+scatter for m in [32b, 32b+32), MLP for same rows.
__global__ __launch_bounds__(256) void rank_mlp_kernel(
    const float* __restrict__ xc, const float* __restrict__ yc,
    const float* __restrict__ W1, const float* __restrict__ b1,
    const float* __restrict__ W2, const float* __restrict__ b2,
    const float* __restrict__ W3, const float* __restrict__ b3,
    float* __restrict__ vT, float* __restrict__ skey, int* __restrict__ perm)
{
    __shared__ float sk[MM];      // all keys, 32 KB
    __shared__ int   red[256];
    const int t = threadIdx.x;
    const int b = blockIdx.x;

    for (int i = t; i < MM; i += 256) sk[i] = xc[i];
    __syncthreads();

    // rank: part = t>>5 scans keys [1024*part, +1024); ml = t&31 picks the row.
    // Within a wave only 2 distinct LDS addresses per read -> broadcast, free.
    {
        const int part = t >> 5, ml = t & 31;
        const int m = b * 32 + ml;
        const float mk = sk[m];
        const int base = part * 1024;
        int cnt = 0;
#pragma unroll 4
        for (int j = 0; j < 1024; j += 4) {
            float4 k4 = *(const float4*)(sk + base + j);
            const int g = base + j;
            // strict total order on (key, index) -> rank is a permutation
            cnt += (k4.x < mk || (k4.x == mk && (g + 0) < m)) ? 1 : 0;
            cnt += (k4.y < mk || (k4.y == mk && (g + 1) < m)) ? 1 : 0;
            cnt += (k4.z < mk || (k4.z == mk && (g + 2) < m)) ? 1 : 0;
            cnt += (k4.w < mk || (k4.w == mk && (g + 3) < m)) ? 1 : 0;
        }
        red[t] = cnt;
    }
    __syncthreads();
    if (t < 32) {
        const int m = b * 32 + t;
        int r = 0;
#pragma unroll
        for (int p = 0; p < 8; p++) r += red[p * 32 + t];
        skey[r] = sk[m];
        perm[r] = m;
    }

    // MLP: 8 threads per row; each computes h1,h2 (redundant) + 8 channels.
    {
        const int ml = t >> 3, part = t & 7;
        const int m = b * 32 + ml;
        const float x = sk[m], y = yc[m];
        float h1[H], h2[H];
#pragma unroll
        for (int j = 0; j < H; j++) {
            float a = x * W1[j] + y * W1[H + j] + b1[j];
            h1[j] = a > 0.f ? a : 0.f;
        }
#pragma unroll
        for (int j = 0; j < H; j++) {
            float a = b2[j];
#pragma unroll
            for (int i = 0; i < H; i++) a += h1[i] * W2[i * H + j];
            h2[j] = a > 0.f ? a : 0.f;
        }
        const int cb = part * 8;
        float acc[8];
#pragma unroll
        for (int c = 0; c < 8; c++) acc[c] = b3[cb + c];
#pragma unroll
        for (int i = 0; i < H; i++) {
            const float h = h2[i];
#pragma unroll
            for (int c = 0; c < 8; c++) acc[c] += h * W3[i * OUTD + cb + c];
        }
#pragma unroll
        for (int c = 0; c < 8; c++) vT[(size_t)(cb + c) * MM + m] = acc[c];
    }
}

// ---------------------------------------------------------------- K2
// 256 blocks = 64 channels x 4 target-quarters. Stage skey + value row in
// LDS, scan Lo/Hi in LDS, answer 2048 targets from LDS. ~132KB LDS, 1 blk/CU.
__global__ __launch_bounds__(256) void scan_query_kernel(
    const float* __restrict__ xt, const float* __restrict__ skey,
    const int* __restrict__ perm, const float* __restrict__ vT,
    float* __restrict__ out)
{
    __shared__ float sk [PAD(MM) + 1];
    __shared__ float sLo[PAD(MM) + 1];
    __shared__ float sHi[PAD(MM) + 1];
    __shared__ float sv [MM];          // value row, gathered via LDS not global
    __shared__ float red[256];
    const int t = threadIdx.x;
    const int c = blockIdx.x & 63;
    const int quarter = blockIdx.x >> 6;
    const float* __restrict__ vrow = vT + (size_t)c * MM;

    for (int i = t; i < MM; i += 256) {   // both coalesced; sk pad-strided
        sk[PAD(i)] = skey[i];
        sv[i] = vrow[i];
    }
    __syncthreads();

    const int base = t * 32;
    float vv[32];                         // gather ONCE, reuse for Lo and Hi
    {
        const int4* pp = (const int4*)(perm + base);
#pragma unroll
        for (int r4 = 0; r4 < 8; r4++) {
            int4 p4 = pp[r4];
            vv[r4 * 4 + 0] = sv[p4.x]; vv[r4 * 4 + 1] = sv[p4.y];
            vv[r4 * 4 + 2] = sv[p4.z]; vv[r4 * 4 + 3] = sv[p4.w];
        }
    }

    // ---- Lo: exclusive prefix of e^{s} v
    float w[32];
    float S = 0.f;
#pragma unroll 4
    for (int r = 0; r < 32; r++) {
        float wv = __expf(sk[PAD(base + r)]) * vv[r];
        w[r] = wv; S += wv;
    }
    red[t] = S;
    __syncthreads();
    for (int off = 1; off < 256; off <<= 1) {      // inclusive prefix scan
        float a = (t >= off) ? red[t - off] : 0.f;
        __syncthreads();
        red[t] += a;
        __syncthreads();
    }
    float run = red[t] - S;                         // exclusive chunk offset
#pragma unroll 4
    for (int r = 0; r < 32; r++) { sLo[PAD(base + r)] = run; run += w[r]; }
    if (t == 255) sLo[PAD(MM)] = run;
    __syncthreads();                                // red reuse barrier

    // ---- Hi: suffix of e^{-s} v
    float S2 = 0.f;
#pragma unroll 4
    for (int r = 0; r < 32; r++) {
        float wv = __expf(-sk[PAD(base + r)]) * vv[r];
        w[r] = wv; S2 += wv;
    }
    red[t] = S2;
    __syncthreads();
    for (int off = 1; off < 256; off <<= 1) {      // inclusive suffix scan
        float a = (t + off < 256) ? red[t + off] : 0.f;
        __syncthreads();
        red[t] += a;
        __syncthreads();
    }
    run = red[t] - S2;                              // sum of chunks after t
#pragma unroll 4
    for (int r = 31; r >= 0; r--) { run += w[r]; sHi[PAD(base + r)] = run; }
    if (t == 0) sHi[PAD(MM)] = 0.f;
    __syncthreads();

    // ---- query: 13-step lower_bound in LDS (8 independent chains/thread
    // for ILP), then 2 LDS reads + 2 expf + global store.
    const int n0 = quarter * (MM / 4);
#pragma unroll
    for (int k = 0; k < MM / 4 / 256; k++) {
        const int n = n0 + k * 256 + t;
        const float q = xt[n];
        int lo = 0, hi = MM;
        while (lo < hi) {
            const int mid = (lo + hi) >> 1;
            if (sk[PAD(mid)] < q) lo = mid + 1; else hi = mid;
        }
        out[(size_t)n * OUTD + c] = __expf(-q) * sLo[PAD(lo)]
                                  + __expf(q)  * sHi[PAD(lo)];
    }
}

extern "C" void kernel_launch(void* const* d_in, const int* in_sizes, int n_in,
                              void* d_out, int out_size, void* d_ws, size_t ws_size,
                              hipStream_t stream)
{
    const float* xc = (const float*)d_in[0];
    const float* yc = (const float*)d_in[1];
    const float* xt = (const float*)d_in[2];
    const float* W1 = (const float*)d_in[3];
    const float* b1 = (const float*)d_in[4];
    const float* W2 = (const float*)d_in[5];
    const float* b2 = (const float*)d_in[6];
    const float* W3 = (const float*)d_in[7];
    const float* b3 = (const float*)d_in[8];
    float* out = (float*)d_out;

    // workspace: vT [64][MM] (2MB) | skey [MM] | perm [MM]
    char* ws = (char*)d_ws;
    float* vT   = (float*)ws;
    float* skey = (float*)(ws + (size_t)OUTD * MM * 4);
    int*   perm = (int*)  (ws + (size_t)OUTD * MM * 4 + (size_t)MM * 4);

    rank_mlp_kernel<<<256, 256, 0, stream>>>(xc, yc, W1, b1, W2, b2, W3, b3,
                                             vT, skey, perm);
    scan_query_kernel<<<256, 256, 0, stream>>>(xt, skey, perm, vT, out);
}

// Round 5
// 99.529 us; speedup vs baseline: 4.5009x; 1.2442x over previous
//
#include <hip/hip_runtime.h>

// DeterministicEncoder: MLP encoder [M,2]->[M,64] + Laplace-kernel attention.
// exp(-|k-q|) factorizes: with context sorted by key, exclusive-prefix
// Lo[j] = sum_{i<j} e^{s_i} v_i and suffix Hi[j] = sum_{i>=j} e^{-s_i} v_i give
// out[n] = e^{-q} Lo[j_n] + e^{q} Hi[j_n], j_n = lower_bound(skey, q).
//
// Round 5: round-4 counters showed K1 at 45us with Occupancy=10%, VALUBusy=21%
// -- latency-bound at 1 wave/SIMD (256-thread blocks, 1 block/CU). Both
// kernels go to 1024-thread blocks (16 waves/CU = 4/SIMD) with identical
// total work; K2's LDS Hillis-Steele scan becomes a wave-shfl scan (3
// barriers instead of ~34, zero scan LDS traffic).

#define H    16
#define OUTD 64
#define MM   8192                 // context/target count, fixed by harness
#define PAD(i) ((i) + ((i) >> 5)) // LDS bank padding

// ---------------------------------------------------------------- K1
// 256 blocks x 1024. Block b: rank+scatter rows [32b,32b+32), MLP same rows.
__global__ __launch_bounds__(1024) void rank_mlp_kernel(
    const float* __restrict__ xc, const float* __restrict__ yc,
    const float* __restrict__ W1, const float* __restrict__ b1,
    const float* __restrict__ W2, const float* __restrict__ b2,
    const float* __restrict__ W3, const float* __restrict__ b3,
    float* __restrict__ vT, float* __restrict__ skey, int* __restrict__ perm)
{
    __shared__ float sk[MM];          // all keys, 32 KB
    __shared__ int   red[32 * 33];    // [part][row], padded stride 33
    const int t = threadIdx.x;
    const int b = blockIdx.x;

    for (int i = t; i < MM; i += 1024) sk[i] = xc[i];
    __syncthreads();

    // rank: part = t>>5 scans keys [256*part, +256); ml = t&31 picks the row.
    // A wave sees 2 distinct LDS addresses per read -> 2-way broadcast, free.
    {
        const int part = t >> 5, ml = t & 31;
        const int m = b * 32 + ml;
        const float mk = sk[m];
        const int base = part * 256;
        int cnt = 0;
#pragma unroll 4
        for (int j = 0; j < 256; j += 4) {
            float4 k4 = *(const float4*)(sk + base + j);
            const int g = base + j;
            // strict total order on (key, index) -> rank is a permutation
            cnt += (k4.x < mk || (k4.x == mk && (g + 0) < m)) ? 1 : 0;
            cnt += (k4.y < mk || (k4.y == mk && (g + 1) < m)) ? 1 : 0;
            cnt += (k4.z < mk || (k4.z == mk && (g + 2) < m)) ? 1 : 0;
            cnt += (k4.w < mk || (k4.w == mk && (g + 3) < m)) ? 1 : 0;
        }
        red[part * 33 + ml] = cnt;
    }
    __syncthreads();
    if (t < 32) {                      // stride-33 reads: conflict-free
        const int m = b * 32 + t;
        int r = 0;
#pragma unroll
        for (int p = 0; p < 32; p++) r += red[p * 33 + t];
        skey[r] = sk[m];
        perm[r] = m;
    }

    // MLP: 32 threads per row; h1/h2 redundant per thread, 2 channels each.
    {
        const int ml = t >> 5, chp = t & 31;
        const int m = b * 32 + ml;
        const float x = sk[m], y = yc[m];
        float h1[H], h2[H];
#pragma unroll
        for (int j = 0; j < H; j++) {
            float a = x * W1[j] + y * W1[H + j] + b1[j];
            h1[j] = a > 0.f ? a : 0.f;
        }
#pragma unroll
        for (int j = 0; j < H; j++) {
            float a = b2[j];
#pragma unroll
            for (int i = 0; i < H; i++) a += h1[i] * W2[i * H + j];
            h2[j] = a > 0.f ? a : 0.f;
        }
        const int cb = chp * 2;
        float a0 = b3[cb], a1 = b3[cb + 1];
#pragma unroll
        for (int i = 0; i < H; i++) {
            const float h = h2[i];
            a0 += h * W3[i * OUTD + cb];
            a1 += h * W3[i * OUTD + cb + 1];
        }
        vT[(size_t)cb * MM + m]       = a0;
        vT[(size_t)(cb + 1) * MM + m] = a1;
    }
}

// ---------------------------------------------------------------- K2
// 256 blocks x 1024 = 64 channels x 4 target-quarters. Stage skey + value row
// in LDS, wave-shfl Lo/Hi scans, answer 2048 targets from LDS. ~134KB LDS.
__global__ __launch_bounds__(1024) void scan_query_kernel(
    const float* __restrict__ xt, const float* __restrict__ skey,
    const int* __restrict__ perm, const float* __restrict__ vT,
    float* __restrict__ out)
{
    __shared__ float sk [PAD(MM) + 1];
    __shared__ float sLo[PAD(MM) + 1];
    __shared__ float sHi[PAD(MM) + 1];
    __shared__ float sv [MM];          // value row for this channel
    __shared__ float wsA[16], wsB[16]; // per-wave scan totals (Lo / Hi)
    const int t = threadIdx.x;
    const int lane = t & 63, wid = t >> 6;
    const int c = blockIdx.x & 63;
    const int quarter = blockIdx.x >> 6;
    const float* __restrict__ vrow = vT + (size_t)c * MM;

    for (int i = t; i < MM; i += 1024) {   // coalesced; sk pad-strided
        sk[PAD(i)] = skey[i];
        sv[i] = vrow[i];
    }
    __syncthreads();

    const int base = t * 8;
    float vv[8], ks[8];
    {
        const int4* pp = (const int4*)(perm + base);
        int4 p0 = pp[0], p1 = pp[1];
        vv[0] = sv[p0.x]; vv[1] = sv[p0.y]; vv[2] = sv[p0.z]; vv[3] = sv[p0.w];
        vv[4] = sv[p1.x]; vv[5] = sv[p1.y]; vv[6] = sv[p1.z]; vv[7] = sv[p1.w];
    }
#pragma unroll
    for (int r = 0; r < 8; r++) ks[r] = sk[PAD(base + r)];

    // ---- Lo: exclusive prefix of e^{s} v
    float w[8];
    float S = 0.f;
#pragma unroll
    for (int r = 0; r < 8; r++) { w[r] = __expf(ks[r]) * vv[r]; S += w[r]; }
    float inc = S;                         // wave inclusive scan (from left)
#pragma unroll
    for (int off = 1; off < 64; off <<= 1) {
        float a = __shfl_up(inc, (unsigned)off);
        if (lane >= off) inc += a;
    }
    if (lane == 63) wsA[wid] = inc;
    __syncthreads();
    float before = 0.f;
#pragma unroll
    for (int ww = 0; ww < 16; ww++) before += (ww < wid) ? wsA[ww] : 0.f;
    float run = before + inc - S;          // exclusive offset of this chunk
#pragma unroll
    for (int r = 0; r < 8; r++) { sLo[PAD(base + r)] = run; run += w[r]; }
    if (t == 1023) sLo[PAD(MM)] = run;

    // ---- Hi: suffix of e^{-s} v
    float S2 = 0.f;
#pragma unroll
    for (int r = 0; r < 8; r++) { w[r] = __expf(-ks[r]) * vv[r]; S2 += w[r]; }
    float inc2 = S2;                       // wave inclusive scan (from right)
#pragma unroll
    for (int off = 1; off < 64; off <<= 1) {
        float a = __shfl_down(inc2, (unsigned)off);
        if (lane + off < 64) inc2 += a;
    }
    if (lane == 0) wsB[wid] = inc2;
    __syncthreads();
    float after = 0.f;
#pragma unroll
    for (int ww = 0; ww < 16; ww++) after += (ww > wid) ? wsB[ww] : 0.f;
    float run2 = after + inc2 - S2;        // sum strictly after this chunk
#pragma unroll
    for (int r = 7; r >= 0; r--) { run2 += w[r]; sHi[PAD(base + r)] = run2; }
    if (t == 0) sHi[PAD(MM)] = 0.f;
    __syncthreads();

    // ---- query: 13-step lower_bound in LDS, 2 LDS reads + 2 expf + store.
    const int n0 = quarter * (MM / 4);
#pragma unroll
    for (int k = 0; k < MM / 4 / 1024; k++) {
        const int n = n0 + k * 1024 + t;
        const float q = xt[n];
        int lo = 0, hi = MM;
        while (lo < hi) {
            const int mid = (lo + hi) >> 1;
            if (sk[PAD(mid)] < q) lo = mid + 1; else hi = mid;
        }
        out[(size_t)n * OUTD + c] = __expf(-q) * sLo[PAD(lo)]
                                  + __expf(q)  * sHi[PAD(lo)];
    }
}

extern "C" void kernel_launch(void* const* d_in, const int* in_sizes, int n_in,
                              void* d_out, int out_size, void* d_ws, size_t ws_size,
                              hipStream_t stream)
{
    const float* xc = (const float*)d_in[0];
    const float* yc = (const float*)d_in[1];
    const float* xt = (const float*)d_in[2];
    const float* W1 = (const float*)d_in[3];
    const float* b1 = (const float*)d_in[4];
    const float* W2 = (const float*)d_in[5];
    const float* b2 = (const float*)d_in[6];
    const float* W3 = (const float*)d_in[7];
    const float* b3 = (const float*)d_in[8];
    float* out = (float*)d_out;

    // workspace: vT [64][MM] (2MB) | skey [MM] | perm [MM]
    char* ws = (char*)d_ws;
    float* vT   = (float*)ws;
    float* skey = (float*)(ws + (size_t)OUTD * MM * 4);
    int*   perm = (int*)  (ws + (size_t)OUTD * MM * 4 + (size_t)MM * 4);

    rank_mlp_kernel<<<256, 1024, 0, stream>>>(xc, yc, W1, b1, W2, b2, W3, b3,
                                              vT, skey, perm);
    scan_query_kernel<<<256, 1024, 0, stream>>>(xt, skey, perm, vT, out);
}

// Round 6
// 95.294 us; speedup vs baseline: 4.7009x; 1.0444x over previous
//
#include <hip/hip_runtime.h>

// DeterministicEncoder: MLP encoder [M,2]->[M,64] + Laplace-kernel attention.
// exp(-|k-q|) factorizes: with context sorted by key, exclusive-prefix
// Lo[j] = sum_{i<j} e^{s_i} v_i and suffix Hi[j] = sum_{i>=j} e^{-s_i} v_i give
// out[n] = e^{-q} Lo[j_n] + e^{q} Hi[j_n], j_n = lower_bound(skey, q).
//
// Round 6: K1 rank restructured to wave-owned rows (8 rows x quarter-keys per
// wave, conflict-free contiguous b128 LDS reads: 128 issues/block vs 1024
// broadcast issues) + shfl-reduced ranks; MLP h1/h2 computed once per row
// (was 32x redundant). K2: float4 value staging + interleaved dual binary
// search for ILP. Two plain dispatches (grid.sync costs ~100us+, round 2).

#define H    16
#define OUTD 64
#define MM   8192                 // context/target count, fixed by harness
#define PAD(i) ((i) + ((i) >> 5)) // LDS bank padding

// ---------------------------------------------------------------- K1
// 256 blocks x 1024. Block b: rank+scatter rows [32b,32b+32), MLP same rows.
__global__ __launch_bounds__(1024) void rank_mlp_kernel(
    const float* __restrict__ xc, const float* __restrict__ yc,
    const float* __restrict__ W1, const float* __restrict__ b1,
    const float* __restrict__ W2, const float* __restrict__ b2,
    const float* __restrict__ W3, const float* __restrict__ b3,
    float* __restrict__ vT, float* __restrict__ skey, int* __restrict__ perm)
{
    __shared__ float sk[MM];          // all keys, 32 KB
    __shared__ int   red[32][4];      // [row][key-quarter] partial ranks
    __shared__ float sh2[32][H + 1];  // h2 per row, padded
    const int t = threadIdx.x;
    const int b = blockIdx.x;
    const int lane = t & 63, wid = t >> 6;

    for (int i = t; i < MM / 4; i += 1024)        // coalesced 16B staging
        ((float4*)sk)[i] = ((const float4*)xc)[i];
    __syncthreads();

    // rank: wave wid -> row-group rg = wid>>2 (8 rows), key-quarter qt = wid&3.
    // Lanes read CONTIGUOUS float4 (64 lanes x 16B = 1KB, conflict-free);
    // each lane compares its 4 keys against all 8 row-keys (broadcast regs).
    {
        const int rg = wid >> 2, qt = wid & 3;
        const int m0 = b * 32 + rg * 8;
        float mk[8];
#pragma unroll
        for (int j = 0; j < 8; j++) mk[j] = sk[m0 + j];   // wave-uniform reads
        int cnt[8] = {0, 0, 0, 0, 0, 0, 0, 0};
#pragma unroll
        for (int ch = 0; ch < 8; ch++) {
            const int g = qt * 2048 + ch * 256 + lane * 4;
            const float4 k4 = *(const float4*)(sk + g);
#pragma unroll
            for (int j = 0; j < 8; j++) {
                const int m = m0 + j;
                const float k = mk[j];
                // strict total order on (key, index) -> rank is a permutation
                cnt[j] += (k4.x < k || (k4.x == k && (g + 0) < m)) ? 1 : 0;
                cnt[j] += (k4.y < k || (k4.y == k && (g + 1) < m)) ? 1 : 0;
                cnt[j] += (k4.z < k || (k4.z == k && (g + 2) < m)) ? 1 : 0;
                cnt[j] += (k4.w < k || (k4.w == k && (g + 3) < m)) ? 1 : 0;
            }
        }
#pragma unroll
        for (int j = 0; j < 8; j++) {            // in-wave reduction
            int v = cnt[j];
#pragma unroll
            for (int off = 32; off; off >>= 1) v += __shfl_down(v, off);
            if (lane == 0) red[rg * 8 + j][qt] = v;
        }
    }

    // MLP stage 1: h2 once per row (t<32), not 32x redundant.
    if (t < 32) {
        const int m = b * 32 + t;
        const float x = sk[m], y = yc[m];
        float h1[H];
#pragma unroll
        for (int j = 0; j < H; j++) {
            float a = x * W1[j] + y * W1[H + j] + b1[j];
            h1[j] = a > 0.f ? a : 0.f;
        }
#pragma unroll
        for (int j = 0; j < H; j++) {
            float a = b2[j];
#pragma unroll
            for (int i = 0; i < H; i++) a += h1[i] * W2[i * H + j];
            sh2[t][j] = a > 0.f ? a : 0.f;
        }
    }
    __syncthreads();

    // scatter (t<32) -- 4-elem sum of partials, then direct sorted write.
    if (t < 32) {
        const int m = b * 32 + t;
        const int r = red[t][0] + red[t][1] + red[t][2] + red[t][3];
        skey[r] = sk[m];
        perm[r] = m;
    }

    // MLP stage 2: 32 threads/row x 2 channels, h2 from LDS (2-addr broadcast).
    {
        const int ml = t >> 5, chp = t & 31;
        const int m = b * 32 + ml;
        const int cb = chp * 2;
        float a0 = b3[cb], a1 = b3[cb + 1];
#pragma unroll
        for (int i = 0; i < H; i++) {
            const float h = sh2[ml][i];
            a0 += h * W3[i * OUTD + cb];
            a1 += h * W3[i * OUTD + cb + 1];
        }
        vT[(size_t)cb * MM + m]       = a0;
        vT[(size_t)(cb + 1) * MM + m] = a1;
    }
}

// ---------------------------------------------------------------- K2
// 256 blocks x 1024 = 64 channels x 4 target-quarters. Stage skey + value row
// in LDS, wave-shfl Lo/Hi scans, answer 2048 targets from LDS. ~134KB LDS.
__global__ __launch_bounds__(1024) void scan_query_kernel(
    const float* __restrict__ xt, const float* __restrict__ skey,
    const int* __restrict__ perm, const float* __restrict__ vT,
    float* __restrict__ out)
{
    __shared__ float sk [PAD(MM) + 1];
    __shared__ float sLo[PAD(MM) + 1];
    __shared__ float sHi[PAD(MM) + 1];
    __shared__ float sv [MM];          // value row for this channel
    __shared__ float wsA[16], wsB[16]; // per-wave scan totals (Lo / Hi)
    const int t = threadIdx.x;
    const int lane = t & 63, wid = t >> 6;
    const int c = blockIdx.x & 63;
    const int quarter = blockIdx.x >> 6;
    const float* __restrict__ vrow = vT + (size_t)c * MM;

    for (int i = t; i < MM / 4; i += 1024) {    // coalesced 16B staging
        ((float4*)sv)[i] = ((const float4*)vrow)[i];
        const float4 k4 = ((const float4*)skey)[i];
        sk[PAD(4 * i + 0)] = k4.x; sk[PAD(4 * i + 1)] = k4.y;
        sk[PAD(4 * i + 2)] = k4.z; sk[PAD(4 * i + 3)] = k4.w;
    }
    __syncthreads();

    const int base = t * 8;
    float vv[8], ks[8];
    {
        const int4* pp = (const int4*)(perm + base);
        int4 p0 = pp[0], p1 = pp[1];
        vv[0] = sv[p0.x]; vv[1] = sv[p0.y]; vv[2] = sv[p0.z]; vv[3] = sv[p0.w];
        vv[4] = sv[p1.x]; vv[5] = sv[p1.y]; vv[6] = sv[p1.z]; vv[7] = sv[p1.w];
    }
#pragma unroll
    for (int r = 0; r < 8; r++) ks[r] = sk[PAD(base + r)];

    // ---- Lo: exclusive prefix of e^{s} v
    float w[8];
    float S = 0.f;
#pragma unroll
    for (int r = 0; r < 8; r++) { w[r] = __expf(ks[r]) * vv[r]; S += w[r]; }
    float inc = S;                         // wave inclusive scan (from left)
#pragma unroll
    for (int off = 1; off < 64; off <<= 1) {
        float a = __shfl_up(inc, (unsigned)off);
        if (lane >= off) inc += a;
    }
    if (lane == 63) wsA[wid] = inc;
    __syncthreads();
    float before = 0.f;
#pragma unroll
    for (int ww = 0; ww < 16; ww++) before += (ww < wid) ? wsA[ww] : 0.f;
    float run = before + inc - S;          // exclusive offset of this chunk
#pragma unroll
    for (int r = 0; r < 8; r++) { sLo[PAD(base + r)] = run; run += w[r]; }
    if (t == 1023) sLo[PAD(MM)] = run;

    // ---- Hi: suffix of e^{-s} v
    float S2 = 0.f;
#pragma unroll
    for (int r = 0; r < 8; r++) { w[r] = __expf(-ks[r]) * vv[r]; S2 += w[r]; }
    float inc2 = S2;                       // wave inclusive scan (from right)
#pragma unroll
    for (int off = 1; off < 64; off <<= 1) {
        float a = __shfl_down(inc2, (unsigned)off);
        if (lane + off < 64) inc2 += a;
    }
    if (lane == 0) wsB[wid] = inc2;
    __syncthreads();
    float after = 0.f;
#pragma unroll
    for (int ww = 0; ww < 16; ww++) after += (ww > wid) ? wsB[ww] : 0.f;
    float run2 = after + inc2 - S2;        // sum strictly after this chunk
#pragma unroll
    for (int r = 7; r >= 0; r--) { run2 += w[r]; sHi[PAD(base + r)] = run2; }
    if (t == 0) sHi[PAD(MM)] = 0.f;
    __syncthreads();

    // ---- query: two interleaved 13-step lower_bounds (independent dependent-
    // LDS chains -> 2x ILP), then 2 LDS reads + 2 expf + store each.
    const int n0 = quarter * (MM / 4) + t;
    const int n1 = n0 + 1024;
    const float q0 = xt[n0], q1 = xt[n1];
    int lo0 = 0, hi0 = MM, lo1 = 0, hi1 = MM;
#pragma unroll
    for (int s = 0; s < 13; s++) {         // 8192 = 2^13: exactly 13 steps
        const int mid0 = (lo0 + hi0) >> 1;
        const int mid1 = (lo1 + hi1) >> 1;
        if (sk[PAD(mid0)] < q0) lo0 = mid0 + 1; else hi0 = mid0;
        if (sk[PAD(mid1)] < q1) lo1 = mid1 + 1; else hi1 = mid1;
    }
    out[(size_t)n0 * OUTD + c] = __expf(-q0) * sLo[PAD(lo0)]
                               + __expf(q0)  * sHi[PAD(lo0)];
    out[(size_t)n1 * OUTD + c] = __expf(-q1) * sLo[PAD(lo1)]
                               + __expf(q1)  * sHi[PAD(lo1)];
}

extern "C" void kernel_launch(void* const* d_in, const int* in_sizes, int n_in,
                              void* d_out, int out_size, void* d_ws, size_t ws_size,
                              hipStream_t stream)
{
    const float* xc = (const float*)d_in[0];
    const float* yc = (const float*)d_in[1];
    const float* xt = (const float*)d_in[2];
    const float* W1 = (const float*)d_in[3];
    const float* b1 = (const float*)d_in[4];
    const float* W2 = (const float*)d_in[5];
    const float* b2 = (const float*)d_in[6];
    const float* W3 = (const float*)d_in[7];
    const float* b3 = (const float*)d_in[8];
    float* out = (float*)d_out;

    // workspace: vT [64][MM] (2MB) | skey [MM] | perm [MM]
    char* ws = (char*)d_ws;
    float* vT   = (float*)ws;
    float* skey = (float*)(ws + (size_t)OUTD * MM * 4);
    int*   perm = (int*)  (ws + (size_t)OUTD * MM * 4 + (size_t)MM * 4);

    rank_mlp_kernel<<<256, 1024, 0, stream>>>(xc, yc, W1, b1, W2, b2, W3, b3,
                                              vT, skey, perm);
    scan_query_kernel<<<256, 1024, 0, stream>>>(xt, skey, perm, vT, out);
}